// Round 2
// baseline (868.350 us; speedup 1.0000x reference)
//
#include <hip/hip_runtime.h>

typedef unsigned short u16;
typedef unsigned int u32;
typedef long long ll;
typedef __attribute__((ext_vector_type(8))) short bf16x8;
typedef __attribute__((ext_vector_type(8))) unsigned short u16x8;
typedef __attribute__((ext_vector_type(4))) float f32x4;

__device__ __forceinline__ u16 f2bf(float f) {
  u32 x = __float_as_uint(f);
  x += 0x7fffu + ((x >> 16) & 1u);
  return (u16)(x >> 16);
}
__device__ __forceinline__ float bf2f(u16 u) {
  return __uint_as_float(((u32)u) << 16);
}

// Read pad index for batch z, auto-detecting int32 vs int64 storage.
// int64 little-endian: odd int32 words (high halves) are all 0.
// (16 random values in [0,2048) being all-zero at odd slots: P ~ 2^-88.)
__device__ __forceinline__ int read_pad(const int* pw, int z) {
  int odd = pw[1] | pw[3] | pw[5] | pw[7] | pw[9] | pw[11] | pw[13] | pw[15];
  return (odd == 0) ? pw[2 * z] : pw[z];
}

// ---------------------------------------------------------------------------
// Stage one 128(rows) x 64(k) bf16 tile into LDS with XOR swizzle on the
// 16B slot index: lds byte = r*128 + (slot ^ (r&7))*16.  (G4 pattern)
// ---------------------------------------------------------------------------
template<bool F32>
__device__ __forceinline__ void stage_tile(const void* src, ll base, int ld,
                                           u16* lds, int tid) {
#pragma unroll
  for (int p = 0; p < 4; ++p) {
    int chunk = p * 256 + tid;   // 0..1023
    int r = chunk >> 3;          // 0..127
    int slot = chunk & 7;        // 8 bf16 per 16B slot
    ll g = base + (ll)r * ld + slot * 8;
    u16x8 v;
    if constexpr (F32) {
      const float* s = (const float*)src + g;
      const float4 a = *(const float4*)s;
      const float4 b = *(const float4*)(s + 4);
      v[0] = f2bf(a.x); v[1] = f2bf(a.y); v[2] = f2bf(a.z); v[3] = f2bf(a.w);
      v[4] = f2bf(b.x); v[5] = f2bf(b.y); v[6] = f2bf(b.z); v[7] = f2bf(b.w);
    } else {
      v = *(const u16x8*)((const u16*)src + g);
    }
    int sw = slot ^ (r & 7);
    *(u16x8*)(lds + r * 64 + sw * 8) = v;
  }
}

// ---------------------------------------------------------------------------
// Generic 128x128 tile GEMM:  C = A * B^T   (both A and B stored as rows of
// length Kdim; B rows are the N dimension).  bf16 MFMA 16x16x32, fp32 accum.
// EPI: 0 = scale+mask -> bf16 scores; 1 = plain bf16 store; 2 = +bias fp32.
// blockIdx.z = batch (strides sA/sB/sC in elements).
// ---------------------------------------------------------------------------
template<bool AF32, bool BF32, int EPI>
__global__ __launch_bounds__(256) void gemm_bf16(
    const void* __restrict__ A, const void* __restrict__ B,
    void* __restrict__ C, int Kdim, int lda, int ldb, int ldc,
    ll sA, ll sB, ll sC, const int* __restrict__ pad,
    const float* __restrict__ bias) {
  __shared__ __align__(16) u16 As[128 * 64];
  __shared__ __align__(16) u16 Bs[128 * 64];

  const int tid = threadIdx.x;
  const int z = blockIdx.z;
  const int bm = blockIdx.y * 128;
  const int bn = blockIdx.x * 128;
  const ll abase = (ll)z * sA + (ll)bm * lda;
  const ll bbase = (ll)z * sB + (ll)bn * ldb;

  const int wid = tid >> 6, lane = tid & 63;
  const int wm = (wid >> 1) * 64;   // wave row offset in tile
  const int wn = (wid & 1) * 64;    // wave col offset in tile
  const int lr = lane & 15;         // m (A) / n (B) index within fragment
  const int lg = lane >> 4;         // k-group 0..3

  f32x4 acc[4][4];
#pragma unroll
  for (int i = 0; i < 4; ++i)
#pragma unroll
    for (int j = 0; j < 4; ++j) acc[i][j] = (f32x4)0.0f;

  for (int k0 = 0; k0 < Kdim; k0 += 64) {
    __syncthreads();
    stage_tile<AF32>(A, abase + k0, lda, As, tid);
    stage_tile<BF32>(B, bbase + k0, ldb, Bs, tid);
    __syncthreads();
#pragma unroll
    for (int kk = 0; kk < 2; ++kk) {
      bf16x8 av[4], bv[4];
#pragma unroll
      for (int i = 0; i < 4; ++i) {
        const int ra = wm + i * 16 + lr;
        av[i] = *(const bf16x8*)(As + ra * 64 + (((kk * 4 + lg) ^ (ra & 7)) * 8));
        const int rb = wn + i * 16 + lr;
        bv[i] = *(const bf16x8*)(Bs + rb * 64 + (((kk * 4 + lg) ^ (rb & 7)) * 8));
      }
#pragma unroll
      for (int i = 0; i < 4; ++i)
#pragma unroll
        for (int j = 0; j < 4; ++j)
          acc[i][j] = __builtin_amdgcn_mfma_f32_16x16x32_bf16(av[i], bv[j],
                                                              acc[i][j], 0, 0, 0);
    }
  }

  // epilogue: C/D layout col = lane&15, row = (lane>>4)*4 + reg  (verified)
  int p = 0;
  if constexpr (EPI == 0) p = read_pad(pad, z);
#pragma unroll
  for (int i = 0; i < 4; ++i) {
    const int rowb = bm + wm + i * 16 + 4 * lg;
#pragma unroll
    for (int j = 0; j < 4; ++j) {
      const int col = bn + wn + j * 16 + lr;
#pragma unroll
      for (int rg = 0; rg < 4; ++rg) {
        const int r = rowb + rg;
        float v = acc[i][j][rg];
        if constexpr (EPI == 0) {
          v *= 0.03125f;  // 1/sqrt(1024)
          if (r >= p && col >= p) v = -1e13f;
          ((u16*)C)[(ll)z * sC + (ll)r * ldc + col] = f2bf(v);
        } else if constexpr (EPI == 1) {
          ((u16*)C)[(ll)z * sC + (ll)r * ldc + col] = f2bf(v);
        } else {
          ((float*)C)[(ll)z * sC + (ll)r * ldc + col] = v + bias[col];
        }
      }
    }
  }
}

// ---------------------------------------------------------------------------
// Transpose + fp32->bf16 convert:  src [R][C] fp32  ->  dst [C][R] bf16.
// 64x64 tiles, coalesced on both sides.
// ---------------------------------------------------------------------------
__global__ __launch_bounds__(256) void transpose_cvt(
    const float* __restrict__ src, u16* __restrict__ dst, int R, int C,
    ll sS, ll sD) {
  __shared__ u16 t[64][65];
  const int tid = threadIdx.x;
  const int r0 = blockIdx.y * 64, c0 = blockIdx.x * 64;
  const float* s = src + (ll)blockIdx.z * sS;
  u16* d = dst + (ll)blockIdx.z * sD;
#pragma unroll
  for (int it = 0; it < 16; ++it) {
    const int idx = it * 256 + tid;
    const int r = idx >> 6, c = idx & 63;
    t[r][c] = f2bf(s[(ll)(r0 + r) * C + c0 + c]);
  }
  __syncthreads();
#pragma unroll
  for (int it = 0; it < 16; ++it) {
    const int idx = it * 256 + tid;
    const int rr = idx >> 6, cc = idx & 63;
    d[(ll)(c0 + rr) * R + r0 + cc] = t[cc][rr];
  }
}

// ---------------------------------------------------------------------------
// In-place row softmax over 2048 bf16 entries; one wave per row.
// ---------------------------------------------------------------------------
__global__ __launch_bounds__(256) void softmax_rows(u16* __restrict__ P) {
  const int wid = threadIdx.x >> 6, lane = threadIdx.x & 63;
  const ll row = (ll)blockIdx.x * 4 + wid;
  u16* p = P + row * 2048;
  float s[32];
#pragma unroll
  for (int i = 0; i < 4; ++i) {
    const u16x8 v = *(const u16x8*)(p + i * 512 + lane * 8);
#pragma unroll
    for (int j = 0; j < 8; ++j) s[i * 8 + j] = bf2f(v[j]);
  }
  float m = s[0];
#pragma unroll
  for (int i = 1; i < 32; ++i) m = fmaxf(m, s[i]);
#pragma unroll
  for (int o = 1; o < 64; o <<= 1) m = fmaxf(m, __shfl_xor(m, o));
  float sum = 0.0f;
#pragma unroll
  for (int i = 0; i < 32; ++i) {
    s[i] = __expf(s[i] - m);
    sum += s[i];
  }
#pragma unroll
  for (int o = 1; o < 64; o <<= 1) sum += __shfl_xor(sum, o);
  const float inv = 1.0f / sum;
#pragma unroll
  for (int i = 0; i < 4; ++i) {
    u16x8 v;
#pragma unroll
    for (int j = 0; j < 8; ++j) v[j] = f2bf(s[i * 8 + j] * inv);
    *(u16x8*)(p + i * 512 + lane * 8) = v;
  }
}

// ---------------------------------------------------------------------------
extern "C" void kernel_launch(void* const* d_in, const int* in_sizes, int n_in,
                              void* d_out, int out_size, void* d_ws,
                              size_t ws_size, hipStream_t stream) {
  const float* Q = (const float*)d_in[0];
  const float* Km = (const float*)d_in[1];
  const float* V = (const float*)d_in[2];
  const int* pad = (const int*)d_in[3];
  const float* W = (const float*)d_in[4];
  const float* bias = (const float*)d_in[5];
  float* out = (float*)d_out;

  const int B = 16, S = 2048, D = 1024, E = 1024;
  const ll SS = (ll)S * S, SD = (ll)S * D;

  // d_out doubles as the bf16 score/probability buffer P (exactly 128 MB);
  // the final GEMM overwrites it with the fp32 result.
  u16* P = (u16*)d_out;
  char* ws = (char*)d_ws;

  const size_t szVt = (size_t)B * D * S * 2;  // 64 MB
  const size_t szWt = (size_t)D * E * 2;      // 2 MB
  const size_t szX = (size_t)B * S * D * 2;   // 64 MB
  const bool flat = ws_size >= szVt + szWt + szX;

  if (flat) {
    u16* Vt = (u16*)ws;
    u16* Wt = (u16*)(ws + szVt);
    u16* X = (u16*)(ws + szVt + szWt);

    transpose_cvt<<<dim3(D / 64, S / 64, B), 256, 0, stream>>>(V, Vt, S, D, SD, SD);
    transpose_cvt<<<dim3(E / 64, D / 64, 1), 256, 0, stream>>>(W, Wt, D, E, 0, 0);
    gemm_bf16<true, true, 0><<<dim3(S / 128, S / 128, B), 256, 0, stream>>>(
        Q, Km, P, D, D, D, S, SD, SD, SS, pad, nullptr);
    softmax_rows<<<dim3(B * S / 4), 256, 0, stream>>>(P);
    gemm_bf16<false, false, 1><<<dim3(D / 128, S / 128, B), 256, 0, stream>>>(
        P, Vt, X, S, S, S, D, SS, SD, SD, nullptr, nullptr);
    gemm_bf16<false, false, 2><<<dim3(E / 128, (B * S) / 128, 1), 256, 0, stream>>>(
        X, Wt, out, D, D, D, E, 0, 0, 0, nullptr, bias);
  } else {
    // fallback: per-batch V transpose (needs ws >= 70 MB)
    u16* Wt = (u16*)ws;
    u16* Vtb = (u16*)(ws + szWt);
    u16* X = (u16*)(ws + szWt + (size_t)D * S * 2);

    transpose_cvt<<<dim3(E / 64, D / 64, 1), 256, 0, stream>>>(W, Wt, D, E, 0, 0);
    gemm_bf16<true, true, 0><<<dim3(S / 128, S / 128, B), 256, 0, stream>>>(
        Q, Km, P, D, D, D, S, SD, SD, SS, pad, nullptr);
    softmax_rows<<<dim3(B * S / 4), 256, 0, stream>>>(P);
    for (int b = 0; b < B; ++b) {
      transpose_cvt<<<dim3(D / 64, S / 64, 1), 256, 0, stream>>>(
          V + (ll)b * SD, Vtb, S, D, 0, 0);
      gemm_bf16<false, false, 1><<<dim3(D / 128, S / 128, 1), 256, 0, stream>>>(
          P + (ll)b * SS, Vtb, X + (ll)b * SD, S, S, S, D, 0, 0, 0, nullptr,
          nullptr);
    }
    gemm_bf16<false, false, 2><<<dim3(E / 128, (B * S) / 128, 1), 256, 0, stream>>>(
        X, Wt, out, D, D, D, E, 0, 0, 0, nullptr, bias);
  }
}

// Round 3
// 742.469 us; speedup vs baseline: 1.1695x; 1.1695x over previous
//
#include <hip/hip_runtime.h>

typedef unsigned short u16;
typedef unsigned int u32;
typedef long long ll;
typedef __attribute__((ext_vector_type(8))) short bf16x8;
typedef __attribute__((ext_vector_type(8))) unsigned short u16x8;
typedef __attribute__((ext_vector_type(4))) float f32x4;

__device__ __forceinline__ u16 f2bf(float f) {
  u32 x = __float_as_uint(f);
  x += 0x7fffu + ((x >> 16) & 1u);
  return (u16)(x >> 16);
}
__device__ __forceinline__ float bf2f(u16 u) {
  return __uint_as_float(((u32)u) << 16);
}

// Read pad index for batch z, auto-detecting int32 vs int64 storage.
__device__ __forceinline__ int read_pad(const int* pw, int z) {
  int odd = pw[1] | pw[3] | pw[5] | pw[7] | pw[9] | pw[11] | pw[13] | pw[15];
  return (odd == 0) ? pw[2 * z] : pw[z];
}

// ---------------------------------------------------------------------------
// fp32 -> bf16 elementwise convert (vectorized, BW-bound).
// ---------------------------------------------------------------------------
__global__ __launch_bounds__(256) void cvt_bf16(const float* __restrict__ src,
                                                u16* __restrict__ dst) {
  const ll i = ((ll)blockIdx.x * 256 + threadIdx.x) * 8;
  const float4 a = *(const float4*)(src + i);
  const float4 b = *(const float4*)(src + i + 4);
  u16x8 v;
  v[0] = f2bf(a.x); v[1] = f2bf(a.y); v[2] = f2bf(a.z); v[3] = f2bf(a.w);
  v[4] = f2bf(b.x); v[5] = f2bf(b.y); v[6] = f2bf(b.z); v[7] = f2bf(b.w);
  *(u16x8*)(dst + i) = v;
}

// ---------------------------------------------------------------------------
// m97-structure GEMM: C = A * B^T, bf16 inputs, global_load_lds width=16,
// LINEAR LDS [128][64] (gload_lds writes base+lane*16; no swizzle, rule #21).
// EPI: 1 = bf16 store; 2 = +bias fp32 store.
// ---------------------------------------------------------------------------
template<int EPI>
__global__ __launch_bounds__(256) void gemm_lds(
    const u16* __restrict__ A, const u16* __restrict__ B,
    void* __restrict__ C, int Kdim, int lda, int ldb, int ldc,
    ll sA, ll sB, ll sC, const float* __restrict__ bias) {
  __shared__ __align__(16) u16 As[128 * 64];
  __shared__ __align__(16) u16 Bs[128 * 64];

  const int tid = threadIdx.x;
  const int wid = tid >> 6, lane = tid & 63;
  const int z = blockIdx.z;
  const int bm = blockIdx.y * 128, bn = blockIdx.x * 128;
  const u16* Ab = A + (ll)z * sA + (ll)bm * lda;
  const u16* Bb = B + (ll)z * sB + (ll)bn * ldb;
  const int wm = (wid >> 1) * 64, wn = (wid & 1) * 64;
  const int lr = lane & 15, lg = lane >> 4;

  f32x4 acc[4][4];
#pragma unroll
  for (int i = 0; i < 4; ++i)
#pragma unroll
    for (int j = 0; j < 4; ++j) acc[i][j] = (f32x4)0.0f;

  for (int k0 = 0; k0 < Kdim; k0 += 64) {
    __syncthreads();
#pragma unroll
    for (int p = 0; p < 4; ++p) {
      const int chunk = p * 256 + wid * 64 + lane;  // wave-contiguous
      const int r = chunk >> 3, slot = chunk & 7;
      __builtin_amdgcn_global_load_lds(
          (const __attribute__((address_space(1))) void*)(Ab + (ll)r * lda + k0 + slot * 8),
          (__attribute__((address_space(3))) void*)(As + (p * 256 + wid * 64) * 8),
          16, 0, 0);
      __builtin_amdgcn_global_load_lds(
          (const __attribute__((address_space(1))) void*)(Bb + (ll)r * ldb + k0 + slot * 8),
          (__attribute__((address_space(3))) void*)(Bs + (p * 256 + wid * 64) * 8),
          16, 0, 0);
    }
    __syncthreads();  // compiler drains vmcnt(0) here
#pragma unroll
    for (int kk = 0; kk < 2; ++kk) {
      bf16x8 av[4], bv[4];
#pragma unroll
      for (int i = 0; i < 4; ++i) {
        av[i] = *(const bf16x8*)(As + (wm + i * 16 + lr) * 64 + (kk * 4 + lg) * 8);
        bv[i] = *(const bf16x8*)(Bs + (wn + i * 16 + lr) * 64 + (kk * 4 + lg) * 8);
      }
#pragma unroll
      for (int i = 0; i < 4; ++i)
#pragma unroll
        for (int j = 0; j < 4; ++j)
          acc[i][j] = __builtin_amdgcn_mfma_f32_16x16x32_bf16(av[i], bv[j],
                                                              acc[i][j], 0, 0, 0);
    }
  }

  // C/D layout: col = lane&15, row = (lane>>4)*4 + reg (HW-verified)
#pragma unroll
  for (int i = 0; i < 4; ++i) {
    const int rowb = bm + wm + i * 16 + 4 * lg;
#pragma unroll
    for (int j = 0; j < 4; ++j) {
      const int col = bn + wn + j * 16 + lr;
#pragma unroll
      for (int rg = 0; rg < 4; ++rg) {
        const int r = rowb + rg;
        if constexpr (EPI == 1) {
          ((u16*)C)[(ll)z * sC + (ll)r * ldc + col] = f2bf(acc[i][j][rg]);
        } else {
          ((float*)C)[(ll)z * sC + (ll)r * ldc + col] = acc[i][j][rg] + bias[col];
        }
      }
    }
  }
}

// ---------------------------------------------------------------------------
// Reg-staged fp32-input GEMM (fallback tiers only): C = A * B^T, raw bf16 out.
// XOR-swizzled LDS (reg staging allows it).
// ---------------------------------------------------------------------------
__device__ __forceinline__ void stage_f32(const float* src, ll base, int ld,
                                          u16* lds, int tid) {
#pragma unroll
  for (int p = 0; p < 4; ++p) {
    int chunk = p * 256 + tid;
    int r = chunk >> 3, slot = chunk & 7;
    const float* s = src + base + (ll)r * ld + slot * 8;
    const float4 a = *(const float4*)s;
    const float4 b = *(const float4*)(s + 4);
    u16x8 v;
    v[0] = f2bf(a.x); v[1] = f2bf(a.y); v[2] = f2bf(a.z); v[3] = f2bf(a.w);
    v[4] = f2bf(b.x); v[5] = f2bf(b.y); v[6] = f2bf(b.z); v[7] = f2bf(b.w);
    *(u16x8*)(lds + r * 64 + (slot ^ (r & 7)) * 8) = v;
  }
}

__global__ __launch_bounds__(256) void gemm_f32in(
    const float* __restrict__ A, const float* __restrict__ B,
    u16* __restrict__ C, int Kdim, int lda, int ldb, int ldc,
    ll sA, ll sB, ll sC) {
  __shared__ __align__(16) u16 As[128 * 64];
  __shared__ __align__(16) u16 Bs[128 * 64];
  const int tid = threadIdx.x;
  const int z = blockIdx.z;
  const int bm = blockIdx.y * 128, bn = blockIdx.x * 128;
  const ll abase = (ll)z * sA + (ll)bm * lda;
  const ll bbase = (ll)z * sB + (ll)bn * ldb;
  const int wid = tid >> 6, lane = tid & 63;
  const int wm = (wid >> 1) * 64, wn = (wid & 1) * 64;
  const int lr = lane & 15, lg = lane >> 4;

  f32x4 acc[4][4];
#pragma unroll
  for (int i = 0; i < 4; ++i)
#pragma unroll
    for (int j = 0; j < 4; ++j) acc[i][j] = (f32x4)0.0f;

  for (int k0 = 0; k0 < Kdim; k0 += 64) {
    __syncthreads();
    stage_f32(A, abase + k0, lda, As, tid);
    stage_f32(B, bbase + k0, ldb, Bs, tid);
    __syncthreads();
#pragma unroll
    for (int kk = 0; kk < 2; ++kk) {
      bf16x8 av[4], bv[4];
#pragma unroll
      for (int i = 0; i < 4; ++i) {
        const int ra = wm + i * 16 + lr;
        av[i] = *(const bf16x8*)(As + ra * 64 + (((kk * 4 + lg) ^ (ra & 7)) * 8));
        const int rb = wn + i * 16 + lr;
        bv[i] = *(const bf16x8*)(Bs + rb * 64 + (((kk * 4 + lg) ^ (rb & 7)) * 8));
      }
#pragma unroll
      for (int i = 0; i < 4; ++i)
#pragma unroll
        for (int j = 0; j < 4; ++j)
          acc[i][j] = __builtin_amdgcn_mfma_f32_16x16x32_bf16(av[i], bv[j],
                                                              acc[i][j], 0, 0, 0);
    }
  }
#pragma unroll
  for (int i = 0; i < 4; ++i) {
    const int rowb = bm + wm + i * 16 + 4 * lg;
#pragma unroll
    for (int j = 0; j < 4; ++j) {
      const int col = bn + wn + j * 16 + lr;
#pragma unroll
      for (int rg = 0; rg < 4; ++rg)
        C[(ll)z * sC + (ll)(rowb + rg) * ldc + col] = f2bf(acc[i][j][rg]);
    }
  }
}

// ---------------------------------------------------------------------------
// Transpose + fp32->bf16: src [R][C] fp32 -> dst [C][R] bf16.
// ---------------------------------------------------------------------------
__global__ __launch_bounds__(256) void transpose_cvt(
    const float* __restrict__ src, u16* __restrict__ dst, int R, int C,
    ll sS, ll sD) {
  __shared__ u16 t[64][65];
  const int tid = threadIdx.x;
  const int r0 = blockIdx.y * 64, c0 = blockIdx.x * 64;
  const float* s = src + (ll)blockIdx.z * sS;
  u16* d = dst + (ll)blockIdx.z * sD;
#pragma unroll
  for (int it = 0; it < 16; ++it) {
    const int idx = it * 256 + tid;
    const int r = idx >> 6, c = idx & 63;
    t[r][c] = f2bf(s[(ll)(r0 + r) * C + c0 + c]);
  }
  __syncthreads();
#pragma unroll
  for (int it = 0; it < 16; ++it) {
    const int idx = it * 256 + tid;
    const int rr = idx >> 6, cc = idx & 63;
    d[(ll)(c0 + rr) * R + r0 + cc] = t[cc][rr];
  }
}

// ---------------------------------------------------------------------------
// In-place row softmax with fused scale + pad-mask. One wave per row of 2048.
// ---------------------------------------------------------------------------
__global__ __launch_bounds__(256) void softmax_rows(u16* __restrict__ P,
                                                    const int* __restrict__ pad) {
  const int wid = threadIdx.x >> 6, lane = threadIdx.x & 63;
  const ll row = (ll)blockIdx.x * 4 + wid;
  const int z = (int)(row >> 11);   // S = 2048
  const int r = (int)(row & 2047);
  const int p = read_pad(pad, z);
  const bool rmask = (r >= p);
  u16* ptr = P + row * 2048;
  float s[32];
#pragma unroll
  for (int i = 0; i < 4; ++i) {
    const u16x8 v = *(const u16x8*)(ptr + i * 512 + lane * 8);
#pragma unroll
    for (int j = 0; j < 8; ++j) {
      const int col = i * 512 + lane * 8 + j;
      float x = bf2f(v[j]) * 0.03125f;  // 1/sqrt(1024)
      if (rmask && col >= p) x = -1e13f;
      s[i * 8 + j] = x;
    }
  }
  float m = s[0];
#pragma unroll
  for (int i = 1; i < 32; ++i) m = fmaxf(m, s[i]);
#pragma unroll
  for (int o = 1; o < 64; o <<= 1) m = fmaxf(m, __shfl_xor(m, o));
  float sum = 0.0f;
#pragma unroll
  for (int i = 0; i < 32; ++i) {
    s[i] = __expf(s[i] - m);
    sum += s[i];
  }
#pragma unroll
  for (int o = 1; o < 64; o <<= 1) sum += __shfl_xor(sum, o);
  const float inv = 1.0f / sum;
#pragma unroll
  for (int i = 0; i < 4; ++i) {
    u16x8 v;
#pragma unroll
    for (int j = 0; j < 8; ++j) v[j] = f2bf(s[i * 8 + j] * inv);
    *(u16x8*)(ptr + i * 512 + lane * 8) = v;
  }
}

// ---------------------------------------------------------------------------
extern "C" void kernel_launch(void* const* d_in, const int* in_sizes, int n_in,
                              void* d_out, int out_size, void* d_ws,
                              size_t ws_size, hipStream_t stream) {
  const float* Q = (const float*)d_in[0];
  const float* Km = (const float*)d_in[1];
  const float* V = (const float*)d_in[2];
  const int* pad = (const int*)d_in[3];
  const float* W = (const float*)d_in[4];
  const float* bias = (const float*)d_in[5];
  float* out = (float*)d_out;

  const int B = 16, S = 2048, D = 1024, E = 1024;
  const ll SS = (ll)S * S, SD = (ll)S * D;

  u16* P = (u16*)d_out;   // 128 MB bf16 scores, overwritten by final GEMM
  char* ws = (char*)d_ws;

  const size_t MB64 = (size_t)B * S * D * 2;  // 64 MB (Qb/Kb/Vt/X each)
  const size_t szWt = (size_t)D * E * 2;      // 2 MB

  if (ws_size >= 3 * MB64 + szWt) {
    // Tier A: all-bf16 GEMMs.  X aliases Qb (dead after QK).
    u16* Qb = (u16*)ws;
    u16* Kb = (u16*)(ws + MB64);
    u16* Vt = (u16*)(ws + 2 * MB64);
    u16* Wt = (u16*)(ws + 3 * MB64);
    u16* X = Qb;

    const int nv = (int)(((ll)B * S * D) / (8 * 256));  // 16384 blocks
    cvt_bf16<<<nv, 256, 0, stream>>>(Q, Qb);
    cvt_bf16<<<nv, 256, 0, stream>>>(Km, Kb);
    transpose_cvt<<<dim3(D / 64, S / 64, B), 256, 0, stream>>>(V, Vt, S, D, SD, SD);
    transpose_cvt<<<dim3(E / 64, D / 64, 1), 256, 0, stream>>>(W, Wt, D, E, 0, 0);

    gemm_lds<1><<<dim3(S / 128, S / 128, B), 256, 0, stream>>>(
        Qb, Kb, P, D, D, D, S, SD, SD, SS, nullptr);
    softmax_rows<<<dim3(B * S / 4), 256, 0, stream>>>(P, pad);
    gemm_lds<1><<<dim3(D / 128, S / 128, B), 256, 0, stream>>>(
        P, Vt, X, S, S, S, D, SS, SD, SD, nullptr);
    gemm_lds<2><<<dim3(E / 128, (B * S) / 128, 1), 256, 0, stream>>>(
        X, Wt, out, D, D, D, E, 0, 0, 0, bias);
  } else if (ws_size >= 2 * MB64 + szWt) {
    // Tier B: fp32-input QK, bf16 PV/out.
    u16* Vt = (u16*)ws;
    u16* Wt = (u16*)(ws + MB64);
    u16* X = (u16*)(ws + MB64 + szWt);

    transpose_cvt<<<dim3(D / 64, S / 64, B), 256, 0, stream>>>(V, Vt, S, D, SD, SD);
    transpose_cvt<<<dim3(E / 64, D / 64, 1), 256, 0, stream>>>(W, Wt, D, E, 0, 0);
    gemm_f32in<<<dim3(S / 128, S / 128, B), 256, 0, stream>>>(
        Q, Km, P, D, D, D, S, SD, SD, SS);
    softmax_rows<<<dim3(B * S / 4), 256, 0, stream>>>(P, pad);
    gemm_lds<1><<<dim3(D / 128, S / 128, B), 256, 0, stream>>>(
        P, Vt, X, S, S, S, D, SS, SD, SD, nullptr);
    gemm_lds<2><<<dim3(E / 128, (B * S) / 128, 1), 256, 0, stream>>>(
        X, Wt, out, D, D, D, E, 0, 0, 0, bias);
  } else {
    // Tier C: per-batch V transpose (needs >= 70 MB).
    u16* Wt = (u16*)ws;
    u16* Vtb = (u16*)(ws + szWt);
    u16* X = (u16*)(ws + szWt + (size_t)D * S * 2);

    transpose_cvt<<<dim3(E / 64, D / 64, 1), 256, 0, stream>>>(W, Wt, D, E, 0, 0);
    gemm_f32in<<<dim3(S / 128, S / 128, B), 256, 0, stream>>>(
        Q, Km, P, D, D, D, S, SD, SD, SS);
    softmax_rows<<<dim3(B * S / 4), 256, 0, stream>>>(P, pad);
    for (int b = 0; b < B; ++b) {
      transpose_cvt<<<dim3(D / 64, S / 64, 1), 256, 0, stream>>>(
          V + (ll)b * SD, Vtb, S, D, 0, 0);
      gemm_lds<1><<<dim3(D / 128, S / 128, 1), 256, 0, stream>>>(
          P + (ll)b * SS, Vtb, X + (ll)b * SD, S, S, S, D, 0, 0, 0, nullptr);
    }
    gemm_lds<2><<<dim3(E / 128, (B * S) / 128, 1), 256, 0, stream>>>(
        X, Wt, out, D, D, D, E, 0, 0, 0, bias);
  }
}

// Round 4
// 560.113 us; speedup vs baseline: 1.5503x; 1.3256x over previous
//
#include <hip/hip_runtime.h>

typedef unsigned short u16;
typedef unsigned int u32;
typedef long long ll;
typedef __attribute__((ext_vector_type(8))) short bf16x8;
typedef __attribute__((ext_vector_type(8))) unsigned short u16x8;
typedef __attribute__((ext_vector_type(4))) float f32x4;

__device__ __forceinline__ u16 f2bf(float f) {
  u32 x = __float_as_uint(f);
  x += 0x7fffu + ((x >> 16) & 1u);
  return (u16)(x >> 16);
}
__device__ __forceinline__ float bf2f(u16 u) {
  return __uint_as_float(((u32)u) << 16);
}

__device__ __forceinline__ int read_pad(const int* pw, int z) {
  int odd = pw[1] | pw[3] | pw[5] | pw[7] | pw[9] | pw[11] | pw[13] | pw[15];
  return (odd == 0) ? pw[2 * z] : pw[z];
}

// ===========================================================================
// 256x256 8-phase GEMM (T2+T3+T4+T5).  C = A * B^T, bf16 in, BK=64,
// 8 waves (2M x 4N), per-wave 128x64 output.  LDS 128 KiB, 2-deep dbuf,
// stage unit = [256 rows][32 k] (16 KiB, 2 gload_lds/thread).
// Swizzle: LDS slot s of row r holds k-group (s ^ ((r>>1)&3)) — applied on
// the pre-swizzled GLOBAL source and on the ds_read address (rule #21).
// EPI: 1 = bf16 store; 2 = fp32 + bias.
// ===========================================================================
__device__ __forceinline__ void stage_unit(const u16* gsrc, int gld, u16* dst,
                                           int ks, int wid, int lane) {
  const int rsub = lane >> 2;                                  // row within 16
  const int gk = ks * 32 + (((lane & 3) ^ ((lane >> 3) & 3)) * 8);
#pragma unroll
  for (int q = 0; q < 2; ++q) {
    const int r0 = (q * 8 + wid) * 16;
    __builtin_amdgcn_global_load_lds(
        (const __attribute__((address_space(1))) void*)(gsrc + (ll)(r0 + rsub) * gld + gk),
        (__attribute__((address_space(3))) void*)(dst + r0 * 32),
        16, 0, 0);
  }
}

template<int EPI>
__global__ __launch_bounds__(512, 2) void gemm8(
    const u16* __restrict__ A, const u16* __restrict__ B, void* __restrict__ C,
    int Kdim, int lda, int ldb, int ldc, ll sA, ll sB, ll sC,
    const float* __restrict__ bias, int NX, int NXY, int nwg) {
  __shared__ __align__(16) u16 ldsA[2][2 * 8192];  // [dbuf][ks*8192 + r*32 + s*8]
  __shared__ __align__(16) u16 ldsB[2][2 * 8192];

  // bijective XCD swizzle (m204) + decode
  const int orig = blockIdx.x;
  const int q8 = nwg >> 3, r8 = nwg & 7;
  const int xcd = orig & 7, inner = orig >> 3;
  const int wg = (xcd < r8 ? xcd * (q8 + 1) : r8 * (q8 + 1) + (xcd - r8) * q8) + inner;
  const int z = wg / NXY;
  const int rem = wg - z * NXY;
  const int by = rem / NX;
  const int bx = rem - by * NX;

  const int tid = threadIdx.x;
  const int wid = tid >> 6, lane = tid & 63;
  const int lr = lane & 15, lg = lane >> 4;
  const int wr = wid >> 2;           // wave m-block (0/1) -> rows wr*128..+127
  const int wn64 = (wid & 3) * 64;   // wave n-block
  const int bm = by * 256, bn = bx * 256;
  const u16* Ab = A + (ll)z * sA + (ll)bm * lda;
  const u16* Bb = B + (ll)z * sB + (ll)bn * ldb;

  // per-lane ds_read offset: row = base + lr, slot = lg ^ ((lr>>1)&3)
  const int aoff = lr * 32 + ((lg ^ ((lr >> 1) & 3)) * 8);

  f32x4 acc[8][4];
#pragma unroll
  for (int i = 0; i < 8; ++i)
#pragma unroll
    for (int j = 0; j < 4; ++j) acc[i][j] = (f32x4)0.0f;

  // ---- prologue: stage all 4 units of tile 0 into buf 0 -------------------
#pragma unroll
  for (int p = 0; p < 4; ++p) {
    const int ks = p >> 1;
    if (p & 1) stage_unit(Bb, ldb, &ldsB[0][ks * 8192], ks, wid, lane);
    else       stage_unit(Ab, lda, &ldsA[0][ks * 8192], ks, wid, lane);
  }
  asm volatile("s_waitcnt vmcnt(4)" ::: "memory");  // k0 units landed
  __builtin_amdgcn_s_barrier();

  // ---- main loop: 4 phases per K-tile ------------------------------------
  const int NT = Kdim >> 6;
  for (int t = 0; t < NT; ++t) {
    const int c = t & 1;
    u16* A_cur = &ldsA[c][0];
    u16* B_cur = &ldsB[c][0];
    u16* A_nxt = &ldsA[c ^ 1][0];
    u16* B_nxt = &ldsB[c ^ 1][0];
    const u16* Agn = Ab + (t + 1) * 64;
    const u16* Bgn = Bb + (t + 1) * 64;
    const bool stage = (t + 1 < NT);
    const bool last = (t + 1 == NT);
#pragma unroll
    for (int p = 0; p < 4; ++p) {
      const int ks = p >> 1, mh = p & 1;
      bf16x8 av[4], bv[4];
#pragma unroll
      for (int i = 0; i < 4; ++i) {
        av[i] = *(const bf16x8*)(A_cur + ks * 8192 +
                                 (wr * 128 + (mh * 4 + i) * 16) * 32 + aoff);
        bv[i] = *(const bf16x8*)(B_cur + ks * 8192 + (wn64 + i * 16) * 32 + aoff);
      }
      if (stage) {
        if (p & 1) stage_unit(Bgn, ldb, B_nxt + ks * 8192, ks, wid, lane);
        else       stage_unit(Agn, lda, A_nxt + ks * 8192, ks, wid, lane);
      }
      __builtin_amdgcn_s_barrier();
      asm volatile("s_waitcnt lgkmcnt(0)" ::: "memory");
      __builtin_amdgcn_sched_barrier(0);
      __builtin_amdgcn_s_setprio(1);
#pragma unroll
      for (int i = 0; i < 4; ++i)
#pragma unroll
        for (int j = 0; j < 4; ++j)
          acc[mh * 4 + i][j] = __builtin_amdgcn_mfma_f32_16x16x32_bf16(
              av[i], bv[j], acc[mh * 4 + i][j], 0, 0, 0);
      __builtin_amdgcn_s_setprio(0);
      if (p == 1) {
        if (last) asm volatile("s_waitcnt vmcnt(0)" ::: "memory");
        else      asm volatile("s_waitcnt vmcnt(4)" ::: "memory");
      } else if (p == 3) {
        if (!last) asm volatile("s_waitcnt vmcnt(4)" ::: "memory");
      }
      __builtin_amdgcn_s_barrier();
    }
  }

  // ---- epilogue: C/D layout col = lane&15, row = (lane>>4)*4 + reg --------
#pragma unroll
  for (int mf = 0; mf < 8; ++mf) {
    const int rowb = bm + wr * 128 + mf * 16 + 4 * lg;
#pragma unroll
    for (int nf = 0; nf < 4; ++nf) {
      const int col = bn + wn64 + nf * 16 + lr;
#pragma unroll
      for (int rg = 0; rg < 4; ++rg) {
        const int r = rowb + rg;
        if constexpr (EPI == 1) {
          ((u16*)C)[(ll)z * sC + (ll)r * ldc + col] = f2bf(acc[mf][nf][rg]);
        } else {
          ((float*)C)[(ll)z * sC + (ll)r * ldc + col] = acc[mf][nf][rg] + bias[col];
        }
      }
    }
  }
}

// ===========================================================================
// Prologue / fallback kernels
// ===========================================================================
__global__ __launch_bounds__(256) void cvt_bf16(const float* __restrict__ src,
                                                u16* __restrict__ dst) {
  const ll i = ((ll)blockIdx.x * 256 + threadIdx.x) * 8;
  const float4 a = *(const float4*)(src + i);
  const float4 b = *(const float4*)(src + i + 4);
  u16x8 v;
  v[0] = f2bf(a.x); v[1] = f2bf(a.y); v[2] = f2bf(a.z); v[3] = f2bf(a.w);
  v[4] = f2bf(b.x); v[5] = f2bf(b.y); v[6] = f2bf(b.z); v[7] = f2bf(b.w);
  *(u16x8*)(dst + i) = v;
}

__global__ __launch_bounds__(256) void transpose_cvt(
    const float* __restrict__ src, u16* __restrict__ dst, int R, int C,
    ll sS, ll sD) {
  __shared__ u16 t[64][65];
  const int tid = threadIdx.x;
  const int r0 = blockIdx.y * 64, c0 = blockIdx.x * 64;
  const float* s = src + (ll)blockIdx.z * sS;
  u16* d = dst + (ll)blockIdx.z * sD;
#pragma unroll
  for (int it = 0; it < 16; ++it) {
    const int idx = it * 256 + tid;
    const int r = idx >> 6, c = idx & 63;
    t[r][c] = f2bf(s[(ll)(r0 + r) * C + c0 + c]);
  }
  __syncthreads();
#pragma unroll
  for (int it = 0; it < 16; ++it) {
    const int idx = it * 256 + tid;
    const int rr = idx >> 6, cc = idx & 63;
    d[(ll)(c0 + rr) * R + r0 + cc] = t[cc][rr];
  }
}

__global__ __launch_bounds__(256) void softmax_rows(u16* __restrict__ P,
                                                    const int* __restrict__ pad) {
  const int wid = threadIdx.x >> 6, lane = threadIdx.x & 63;
  const ll row = (ll)blockIdx.x * 4 + wid;
  const int z = (int)(row >> 11);
  const int r = (int)(row & 2047);
  const int p = read_pad(pad, z);
  const bool rmask = (r >= p);
  u16* ptr = P + row * 2048;
  float s[32];
#pragma unroll
  for (int i = 0; i < 4; ++i) {
    const u16x8 v = *(const u16x8*)(ptr + i * 512 + lane * 8);
#pragma unroll
    for (int j = 0; j < 8; ++j) {
      const int col = i * 512 + lane * 8 + j;
      float x = bf2f(v[j]) * 0.03125f;
      if (rmask && col >= p) x = -1e13f;
      s[i * 8 + j] = x;
    }
  }
  float m = s[0];
#pragma unroll
  for (int i = 1; i < 32; ++i) m = fmaxf(m, s[i]);
#pragma unroll
  for (int o = 1; o < 64; o <<= 1) m = fmaxf(m, __shfl_xor(m, o));
  float sum = 0.0f;
#pragma unroll
  for (int i = 0; i < 32; ++i) {
    s[i] = __expf(s[i] - m);
    sum += s[i];
  }
#pragma unroll
  for (int o = 1; o < 64; o <<= 1) sum += __shfl_xor(sum, o);
  const float inv = 1.0f / sum;
#pragma unroll
  for (int i = 0; i < 4; ++i) {
    u16x8 v;
#pragma unroll
    for (int j = 0; j < 8; ++j) v[j] = f2bf(s[i * 8 + j] * inv);
    *(u16x8*)(ptr + i * 512 + lane * 8) = v;
  }
}

// 128² reg-staged fp32-input GEMM (fallback tiers): C = A * B^T, bf16 out.
__device__ __forceinline__ void stage_f32(const float* src, ll base, int ld,
                                          u16* lds, int tid) {
#pragma unroll
  for (int p = 0; p < 4; ++p) {
    int chunk = p * 256 + tid;
    int r = chunk >> 3, slot = chunk & 7;
    const float* s = src + base + (ll)r * ld + slot * 8;
    const float4 a = *(const float4*)s;
    const float4 b = *(const float4*)(s + 4);
    u16x8 v;
    v[0] = f2bf(a.x); v[1] = f2bf(a.y); v[2] = f2bf(a.z); v[3] = f2bf(a.w);
    v[4] = f2bf(b.x); v[5] = f2bf(b.y); v[6] = f2bf(b.z); v[7] = f2bf(b.w);
    *(u16x8*)(lds + r * 64 + (slot ^ (r & 7)) * 8) = v;
  }
}

__global__ __launch_bounds__(256) void gemm_f32in(
    const float* __restrict__ A, const float* __restrict__ B,
    u16* __restrict__ C, int Kdim, int lda, int ldb, int ldc,
    ll sA, ll sB, ll sC) {
  __shared__ __align__(16) u16 As[128 * 64];
  __shared__ __align__(16) u16 Bs[128 * 64];
  const int tid = threadIdx.x;
  const int z = blockIdx.z;
  const int bm = blockIdx.y * 128, bn = blockIdx.x * 128;
  const ll abase = (ll)z * sA + (ll)bm * lda;
  const ll bbase = (ll)z * sB + (ll)bn * ldb;
  const int wid = tid >> 6, lane = tid & 63;
  const int wm = (wid >> 1) * 64, wn = (wid & 1) * 64;
  const int lr = lane & 15, lg = lane >> 4;

  f32x4 acc[4][4];
#pragma unroll
  for (int i = 0; i < 4; ++i)
#pragma unroll
    for (int j = 0; j < 4; ++j) acc[i][j] = (f32x4)0.0f;

  for (int k0 = 0; k0 < Kdim; k0 += 64) {
    __syncthreads();
    stage_f32(A, abase + k0, lda, As, tid);
    stage_f32(B, bbase + k0, ldb, Bs, tid);
    __syncthreads();
#pragma unroll
    for (int kk = 0; kk < 2; ++kk) {
      bf16x8 av[4], bv[4];
#pragma unroll
      for (int i = 0; i < 4; ++i) {
        const int ra = wm + i * 16 + lr;
        av[i] = *(const bf16x8*)(As + ra * 64 + (((kk * 4 + lg) ^ (ra & 7)) * 8));
        const int rb = wn + i * 16 + lr;
        bv[i] = *(const bf16x8*)(Bs + rb * 64 + (((kk * 4 + lg) ^ (rb & 7)) * 8));
      }
#pragma unroll
      for (int i = 0; i < 4; ++i)
#pragma unroll
        for (int j = 0; j < 4; ++j)
          acc[i][j] = __builtin_amdgcn_mfma_f32_16x16x32_bf16(av[i], bv[j],
                                                              acc[i][j], 0, 0, 0);
    }
  }
#pragma unroll
  for (int i = 0; i < 4; ++i) {
    const int rowb = bm + wm + i * 16 + 4 * lg;
#pragma unroll
    for (int j = 0; j < 4; ++j) {
      const int col = bn + wn + j * 16 + lr;
#pragma unroll
      for (int rg = 0; rg < 4; ++rg)
        C[(ll)z * sC + (ll)(rowb + rg) * ldc + col] = f2bf(acc[i][j][rg]);
    }
  }
}

// ===========================================================================
extern "C" void kernel_launch(void* const* d_in, const int* in_sizes, int n_in,
                              void* d_out, int out_size, void* d_ws,
                              size_t ws_size, hipStream_t stream) {
  const float* Q = (const float*)d_in[0];
  const float* Km = (const float*)d_in[1];
  const float* V = (const float*)d_in[2];
  const int* pad = (const int*)d_in[3];
  const float* W = (const float*)d_in[4];
  const float* bias = (const float*)d_in[5];
  float* out = (float*)d_out;

  const int B = 16, S = 2048, D = 1024, E = 1024;
  const ll SS = (ll)S * S, SD = (ll)S * D;

  u16* P = (u16*)d_out;   // 128 MB bf16 scores; final GEMM overwrites
  char* ws = (char*)d_ws;

  const size_t MB64 = (size_t)B * S * D * 2;  // 64 MB
  const size_t szWt = (size_t)D * E * 2;      // 2 MB

  if (ws_size >= 3 * MB64 + szWt) {
    // Tier A: all-bf16, all GEMMs on the 8-phase 256² kernel.
    u16* Qb = (u16*)ws;
    u16* Kb = (u16*)(ws + MB64);
    u16* Vt = (u16*)(ws + 2 * MB64);
    u16* Wt = (u16*)(ws + 3 * MB64);
    u16* X = Qb;  // aliases Qb (dead after QK)

    const int nv = (int)(((ll)B * S * D) / (8 * 256));
    cvt_bf16<<<nv, 256, 0, stream>>>(Q, Qb);
    cvt_bf16<<<nv, 256, 0, stream>>>(Km, Kb);
    transpose_cvt<<<dim3(D / 64, S / 64, B), 256, 0, stream>>>(V, Vt, S, D, SD, SD);
    transpose_cvt<<<dim3(E / 64, D / 64, 1), 256, 0, stream>>>(W, Wt, D, E, 0, 0);

    // QK: M=N=2048, K=1024, 16 batches -> nwg = 8*8*16 = 1024
    gemm8<1><<<dim3(1024), 512, 0, stream>>>(
        Qb, Kb, P, D, D, D, S, SD, SD, SS, nullptr, 8, 64, 1024);
    softmax_rows<<<dim3(B * S / 4), 256, 0, stream>>>(P, pad);
    // PV: M=2048, N=1024, K=2048 -> nwg = 4*8*16 = 512
    gemm8<1><<<dim3(512), 512, 0, stream>>>(
        P, Vt, X, S, S, S, D, SS, SD, SD, nullptr, 4, 32, 512);
    // out: M=32768, N=1024, K=1024 -> nwg = 4*128 = 512
    gemm8<2><<<dim3(512), 512, 0, stream>>>(
        X, Wt, out, D, D, D, E, 0, 0, 0, bias, 4, 512, 512);
  } else if (ws_size >= 2 * MB64 + szWt) {
    // Tier B: fp32-input 128² QK; 8-phase PV/out.
    u16* Vt = (u16*)ws;
    u16* Wt = (u16*)(ws + MB64);
    u16* X = (u16*)(ws + MB64 + szWt);

    transpose_cvt<<<dim3(D / 64, S / 64, B), 256, 0, stream>>>(V, Vt, S, D, SD, SD);
    transpose_cvt<<<dim3(E / 64, D / 64, 1), 256, 0, stream>>>(W, Wt, D, E, 0, 0);
    gemm_f32in<<<dim3(S / 128, S / 128, B), 256, 0, stream>>>(
        Q, Km, P, D, D, D, S, SD, SD, SS);
    softmax_rows<<<dim3(B * S / 4), 256, 0, stream>>>(P, pad);
    gemm8<1><<<dim3(512), 512, 0, stream>>>(
        P, Vt, X, S, S, S, D, SS, SD, SD, nullptr, 4, 32, 512);
    gemm8<2><<<dim3(512), 512, 0, stream>>>(
        X, Wt, out, D, D, D, E, 0, 0, 0, bias, 4, 512, 512);
  } else {
    // Tier C: per-batch V transpose (needs >= 70 MB).
    u16* Wt = (u16*)ws;
    u16* Vtb = (u16*)(ws + szWt);
    u16* X = (u16*)(ws + szWt + (size_t)D * S * 2);

    transpose_cvt<<<dim3(E / 64, D / 64, 1), 256, 0, stream>>>(W, Wt, D, E, 0, 0);
    gemm_f32in<<<dim3(S / 128, S / 128, B), 256, 0, stream>>>(
        Q, Km, P, D, D, D, S, SD, SD, SS);
    softmax_rows<<<dim3(B * S / 4), 256, 0, stream>>>(P, pad);
    for (int b = 0; b < B; ++b) {
      transpose_cvt<<<dim3(D / 64, S / 64, 1), 256, 0, stream>>>(
          V + (ll)b * SD, Vtb, S, D, 0, 0);
      gemm8<1><<<dim3(32), 512, 0, stream>>>(
          P + (ll)b * SS, Vtb, X + (ll)b * SD, S, S, S, D, 0, 0, 0, nullptr,
          4, 32, 32);
    }
    gemm8<2><<<dim3(512), 512, 0, stream>>>(
        X, Wt, out, D, D, D, E, 0, 0, 0, bias, 4, 512, 512);
  }
}

// Round 5
// 525.766 us; speedup vs baseline: 1.6516x; 1.0653x over previous
//
#include <hip/hip_runtime.h>

typedef unsigned short u16;
typedef unsigned int u32;
typedef long long ll;
typedef __attribute__((ext_vector_type(8))) short bf16x8;
typedef __attribute__((ext_vector_type(8))) unsigned short u16x8;
typedef __attribute__((ext_vector_type(4))) float f32x4;

__device__ __forceinline__ u16 f2bf(float f) {
  u32 x = __float_as_uint(f);
  x += 0x7fffu + ((x >> 16) & 1u);
  return (u16)(x >> 16);
}
__device__ __forceinline__ float bf2f(u16 u) {
  return __uint_as_float(((u32)u) << 16);
}

__device__ __forceinline__ int read_pad(const int* pw, int z) {
  int odd = pw[1] | pw[3] | pw[5] | pw[7] | pw[9] | pw[11] | pw[13] | pw[15];
  return (odd == 0) ? pw[2 * z] : pw[z];
}

// ===========================================================================
// 256x256 8-phase GEMM (T1+T2+T3+T4+T5).  C = A * B^T, bf16 in, BK=64,
// 8 waves (2M x 4N), per-wave 128x64 output.  LDS 128 KiB, 2-deep dbuf.
// Phase structure per k-slice (K=32): {read bv+av(mh0) | stage | barrier |
// MFMA | barrier} then {read av(mh1) only (bv cached in regs) | stage |
// barrier | MFMA | vmcnt(4) | barrier}.  No explicit lgkmcnt: compiler emits
// per-fragment waits so LDS streaming overlaps the MFMA cluster.
// EPI: 0 = scale+mask -> bf16; 1 = bf16; 2 = fp32 + bias.
// ===========================================================================
__device__ __forceinline__ void stage_unit(const u16* gsrc, int gld, u16* dst,
                                           int ks, int wid, int lane) {
  const int rsub = lane >> 2;  // row within 16
  const int gk = ks * 32 + (((lane & 3) ^ ((lane >> 3) & 3)) * 8);
#pragma unroll
  for (int q = 0; q < 2; ++q) {
    const int r0 = (q * 8 + wid) * 16;
    __builtin_amdgcn_global_load_lds(
        (const __attribute__((address_space(1))) void*)(gsrc + (ll)(r0 + rsub) * gld + gk),
        (__attribute__((address_space(3))) void*)(dst + r0 * 32),
        16, 0, 0);
  }
}

template<int EPI>
__global__ __launch_bounds__(512, 2) void gemm8(
    const u16* __restrict__ A, const u16* __restrict__ B, void* __restrict__ C,
    int Kdim, int lda, int ldb, int ldc, ll sA, ll sB, ll sC,
    const int* __restrict__ pad, const float* __restrict__ bias,
    int NX, int NXY, int nwg) {
  __shared__ __align__(16) u16 ldsA[2][2 * 8192];  // [dbuf][ks*8192 + r*32 + s*8]
  __shared__ __align__(16) u16 ldsB[2][2 * 8192];

  // bijective XCD swizzle (m204) + decode
  const int orig = blockIdx.x;
  const int q8 = nwg >> 3, r8 = nwg & 7;
  const int xcd = orig & 7, inner = orig >> 3;
  const int wg = (xcd < r8 ? xcd * (q8 + 1) : r8 * (q8 + 1) + (xcd - r8) * q8) + inner;
  const int z = wg / NXY;
  const int rem = wg - z * NXY;
  const int by = rem / NX;
  const int bx = rem - by * NX;

  const int tid = threadIdx.x;
  const int wid = tid >> 6, lane = tid & 63;
  const int lr = lane & 15, lg = lane >> 4;
  const int wr = wid >> 2;          // wave m-block (0/1)
  const int wn64 = (wid & 3) * 64;  // wave n-block
  const int bm = by * 256, bn = bx * 256;
  const u16* Ab = A + (ll)z * sA + (ll)bm * lda;
  const u16* Bb = B + (ll)z * sB + (ll)bn * ldb;

  // per-lane ds_read offset: row = base + lr, slot = lg ^ ((lr>>1)&3)
  const int aoff = lr * 32 + ((lg ^ ((lr >> 1) & 3)) * 8);

  f32x4 acc[8][4];
#pragma unroll
  for (int i = 0; i < 8; ++i)
#pragma unroll
    for (int j = 0; j < 4; ++j) acc[i][j] = (f32x4)0.0f;

  // ---- prologue: stage all 4 units of tile 0 into buf 0 -------------------
#pragma unroll
  for (int p = 0; p < 4; ++p) {
    const int ks = p >> 1;
    if (p & 1) stage_unit(Bb, ldb, &ldsB[0][ks * 8192], ks, wid, lane);
    else       stage_unit(Ab, lda, &ldsA[0][ks * 8192], ks, wid, lane);
  }
  asm volatile("s_waitcnt vmcnt(4)" ::: "memory");  // ks0 units landed
  __builtin_amdgcn_s_barrier();

  // ---- main loop ----------------------------------------------------------
  const int NT = Kdim >> 6;
  for (int t = 0; t < NT; ++t) {
    const int c = t & 1;
    u16* A_cur = &ldsA[c][0];
    u16* B_cur = &ldsB[c][0];
    u16* A_nxt = &ldsA[c ^ 1][0];
    u16* B_nxt = &ldsB[c ^ 1][0];
    const u16* Agn = Ab + (t + 1) * 64;
    const u16* Bgn = Bb + (t + 1) * 64;
    const bool stage = (t + 1 < NT);
    const bool last = (t + 1 == NT);
#pragma unroll
    for (int ks = 0; ks < 2; ++ks) {
      bf16x8 av[4], bv[4];
      // ---- phase A (mh=0): bv + av reads, stage A-unit of next tile -------
#pragma unroll
      for (int i = 0; i < 4; ++i) {
        bv[i] = *(const bf16x8*)(B_cur + ks * 8192 + (wn64 + i * 16) * 32 + aoff);
        av[i] = *(const bf16x8*)(A_cur + ks * 8192 + (wr * 128 + i * 16) * 32 + aoff);
      }
      if (stage) stage_unit(Agn, lda, A_nxt + ks * 8192, ks, wid, lane);
      __builtin_amdgcn_s_barrier();
      __builtin_amdgcn_s_setprio(1);
#pragma unroll
      for (int i = 0; i < 4; ++i)
#pragma unroll
        for (int j = 0; j < 4; ++j)
          acc[i][j] = __builtin_amdgcn_mfma_f32_16x16x32_bf16(
              av[i], bv[j], acc[i][j], 0, 0, 0);
      __builtin_amdgcn_s_setprio(0);
      __builtin_amdgcn_s_barrier();
      // ---- phase B (mh=1): av reads only (bv cached), stage B-unit --------
#pragma unroll
      for (int i = 0; i < 4; ++i)
        av[i] = *(const bf16x8*)(A_cur + ks * 8192 +
                                 (wr * 128 + (4 + i) * 16) * 32 + aoff);
      if (stage) stage_unit(Bgn, ldb, B_nxt + ks * 8192, ks, wid, lane);
      __builtin_amdgcn_s_barrier();
      __builtin_amdgcn_s_setprio(1);
#pragma unroll
      for (int i = 0; i < 4; ++i)
#pragma unroll
        for (int j = 0; j < 4; ++j)
          acc[4 + i][j] = __builtin_amdgcn_mfma_f32_16x16x32_bf16(
              av[i], bv[j], acc[4 + i][j], 0, 0, 0);
      __builtin_amdgcn_s_setprio(0);
      if (ks == 0) {
        if (last) asm volatile("s_waitcnt vmcnt(0)" ::: "memory");
        else      asm volatile("s_waitcnt vmcnt(4)" ::: "memory");
      } else if (!last) {
        asm volatile("s_waitcnt vmcnt(4)" ::: "memory");
      }
      __builtin_amdgcn_s_barrier();
    }
  }

  // ---- epilogue: C/D layout col = lane&15, row = (lane>>4)*4 + reg --------
  int p = 0;
  if constexpr (EPI == 0) p = read_pad(pad, z);
#pragma unroll
  for (int mf = 0; mf < 8; ++mf) {
    const int rowb = bm + wr * 128 + mf * 16 + 4 * lg;
#pragma unroll
    for (int nf = 0; nf < 4; ++nf) {
      const int col = bn + wn64 + nf * 16 + lr;
#pragma unroll
      for (int rg = 0; rg < 4; ++rg) {
        const int r = rowb + rg;
        if constexpr (EPI == 0) {
          float v = acc[mf][nf][rg] * 0.03125f;  // 1/sqrt(1024)
          if (r >= p && col >= p) v = -1e13f;
          ((u16*)C)[(ll)z * sC + (ll)r * ldc + col] = f2bf(v);
        } else if constexpr (EPI == 1) {
          ((u16*)C)[(ll)z * sC + (ll)r * ldc + col] = f2bf(acc[mf][nf][rg]);
        } else {
          ((float*)C)[(ll)z * sC + (ll)r * ldc + col] = acc[mf][nf][rg] + bias[col];
        }
      }
    }
  }
}

// ===========================================================================
// Prologue / fallback kernels
// ===========================================================================
__global__ __launch_bounds__(256) void cvt_bf16(const float* __restrict__ src,
                                                u16* __restrict__ dst) {
  const ll i = ((ll)blockIdx.x * 256 + threadIdx.x) * 8;
  const float4 a = *(const float4*)(src + i);
  const float4 b = *(const float4*)(src + i + 4);
  u16x8 v;
  v[0] = f2bf(a.x); v[1] = f2bf(a.y); v[2] = f2bf(a.z); v[3] = f2bf(a.w);
  v[4] = f2bf(b.x); v[5] = f2bf(b.y); v[6] = f2bf(b.z); v[7] = f2bf(b.w);
  *(u16x8*)(dst + i) = v;
}

__global__ __launch_bounds__(256) void transpose_cvt(
    const float* __restrict__ src, u16* __restrict__ dst, int R, int C,
    ll sS, ll sD) {
  __shared__ u16 t[64][65];
  const int tid = threadIdx.x;
  const int r0 = blockIdx.y * 64, c0 = blockIdx.x * 64;
  const float* s = src + (ll)blockIdx.z * sS;
  u16* d = dst + (ll)blockIdx.z * sD;
#pragma unroll
  for (int it = 0; it < 16; ++it) {
    const int idx = it * 256 + tid;
    const int r = idx >> 6, c = idx & 63;
    t[r][c] = f2bf(s[(ll)(r0 + r) * C + c0 + c]);
  }
  __syncthreads();
#pragma unroll
  for (int it = 0; it < 16; ++it) {
    const int idx = it * 256 + tid;
    const int rr = idx >> 6, cc = idx & 63;
    d[(ll)(c0 + rr) * R + r0 + cc] = t[cc][rr];
  }
}

// In-place row softmax; MASKED variant also applies scale + pad mask
// (used when the producing GEMM didn't).
template<bool MASKED>
__global__ __launch_bounds__(256) void softmax_rows(u16* __restrict__ P,
                                                    const int* __restrict__ pad) {
  const int wid = threadIdx.x >> 6, lane = threadIdx.x & 63;
  const ll row = (ll)blockIdx.x * 4 + wid;
  const int z = (int)(row >> 11);
  const int r = (int)(row & 2047);
  int p = 0;
  bool rmask = false;
  if constexpr (MASKED) {
    p = read_pad(pad, z);
    rmask = (r >= p);
  }
  u16* ptr = P + row * 2048;
  float s[32];
#pragma unroll
  for (int i = 0; i < 4; ++i) {
    const u16x8 v = *(const u16x8*)(ptr + i * 512 + lane * 8);
#pragma unroll
    for (int j = 0; j < 8; ++j) {
      float x = bf2f(v[j]);
      if constexpr (MASKED) {
        const int col = i * 512 + lane * 8 + j;
        x *= 0.03125f;
        if (rmask && col >= p) x = -1e13f;
      }
      s[i * 8 + j] = x;
    }
  }
  float m = s[0];
#pragma unroll
  for (int i = 1; i < 32; ++i) m = fmaxf(m, s[i]);
#pragma unroll
  for (int o = 1; o < 64; o <<= 1) m = fmaxf(m, __shfl_xor(m, o));
  float sum = 0.0f;
#pragma unroll
  for (int i = 0; i < 32; ++i) {
    s[i] = __expf(s[i] - m);
    sum += s[i];
  }
#pragma unroll
  for (int o = 1; o < 64; o <<= 1) sum += __shfl_xor(sum, o);
  const float inv = 1.0f / sum;
#pragma unroll
  for (int i = 0; i < 4; ++i) {
    u16x8 v;
#pragma unroll
    for (int j = 0; j < 8; ++j) v[j] = f2bf(s[i * 8 + j] * inv);
    *(u16x8*)(ptr + i * 512 + lane * 8) = v;
  }
}

// 128² reg-staged fp32-input GEMM (fallback tiers): C = A * B^T, bf16 out.
__device__ __forceinline__ void stage_f32(const float* src, ll base, int ld,
                                          u16* lds, int tid) {
#pragma unroll
  for (int p = 0; p < 4; ++p) {
    int chunk = p * 256 + tid;
    int r = chunk >> 3, slot = chunk & 7;
    const float* s = src + base + (ll)r * ld + slot * 8;
    const float4 a = *(const float4*)s;
    const float4 b = *(const float4*)(s + 4);
    u16x8 v;
    v[0] = f2bf(a.x); v[1] = f2bf(a.y); v[2] = f2bf(a.z); v[3] = f2bf(a.w);
    v[4] = f2bf(b.x); v[5] = f2bf(b.y); v[6] = f2bf(b.z); v[7] = f2bf(b.w);
    *(u16x8*)(lds + r * 64 + (slot ^ (r & 7)) * 8) = v;
  }
}

__global__ __launch_bounds__(256) void gemm_f32in(
    const float* __restrict__ A, const float* __restrict__ B,
    u16* __restrict__ C, int Kdim, int lda, int ldb, int ldc,
    ll sA, ll sB, ll sC) {
  __shared__ __align__(16) u16 As[128 * 64];
  __shared__ __align__(16) u16 Bs[128 * 64];
  const int tid = threadIdx.x;
  const int z = blockIdx.z;
  const int bm = blockIdx.y * 128, bn = blockIdx.x * 128;
  const ll abase = (ll)z * sA + (ll)bm * lda;
  const ll bbase = (ll)z * sB + (ll)bn * ldb;
  const int wid = tid >> 6, lane = tid & 63;
  const int wm = (wid >> 1) * 64, wn = (wid & 1) * 64;
  const int lr = lane & 15, lg = lane >> 4;

  f32x4 acc[4][4];
#pragma unroll
  for (int i = 0; i < 4; ++i)
#pragma unroll
    for (int j = 0; j < 4; ++j) acc[i][j] = (f32x4)0.0f;

  for (int k0 = 0; k0 < Kdim; k0 += 64) {
    __syncthreads();
    stage_f32(A, abase + k0, lda, As, tid);
    stage_f32(B, bbase + k0, ldb, Bs, tid);
    __syncthreads();
#pragma unroll
    for (int kk = 0; kk < 2; ++kk) {
      bf16x8 av[4], bv[4];
#pragma unroll
      for (int i = 0; i < 4; ++i) {
        const int ra = wm + i * 16 + lr;
        av[i] = *(const bf16x8*)(As + ra * 64 + (((kk * 4 + lg) ^ (ra & 7)) * 8));
        const int rb = wn + i * 16 + lr;
        bv[i] = *(const bf16x8*)(Bs + rb * 64 + (((kk * 4 + lg) ^ (rb & 7)) * 8));
      }
#pragma unroll
      for (int i = 0; i < 4; ++i)
#pragma unroll
        for (int j = 0; j < 4; ++j)
          acc[i][j] = __builtin_amdgcn_mfma_f32_16x16x32_bf16(av[i], bv[j],
                                                              acc[i][j], 0, 0, 0);
    }
  }
#pragma unroll
  for (int i = 0; i < 4; ++i) {
    const int rowb = bm + wm + i * 16 + 4 * lg;
#pragma unroll
    for (int j = 0; j < 4; ++j) {
      const int col = bn + wn + j * 16 + lr;
#pragma unroll
      for (int rg = 0; rg < 4; ++rg)
        C[(ll)z * sC + (ll)(rowb + rg) * ldc + col] = f2bf(acc[i][j][rg]);
    }
  }
}

// ===========================================================================
extern "C" void kernel_launch(void* const* d_in, const int* in_sizes, int n_in,
                              void* d_out, int out_size, void* d_ws,
                              size_t ws_size, hipStream_t stream) {
  const float* Q = (const float*)d_in[0];
  const float* Km = (const float*)d_in[1];
  const float* V = (const float*)d_in[2];
  const int* pad = (const int*)d_in[3];
  const float* W = (const float*)d_in[4];
  const float* bias = (const float*)d_in[5];
  float* out = (float*)d_out;

  const int B = 16, S = 2048, D = 1024, E = 1024;
  const ll SS = (ll)S * S, SD = (ll)S * D;

  u16* P = (u16*)d_out;   // 128 MB bf16 scores; final GEMM overwrites
  char* ws = (char*)d_ws;

  const size_t MB64 = (size_t)B * S * D * 2;  // 64 MB
  const size_t szWt = (size_t)D * E * 2;      // 2 MB

  if (ws_size >= 3 * MB64 + szWt) {
    // Tier A: all-bf16, all GEMMs on the 8-phase 256² kernel.
    u16* Qb = (u16*)ws;
    u16* Kb = (u16*)(ws + MB64);
    u16* Vt = (u16*)(ws + 2 * MB64);
    u16* Wt = (u16*)(ws + 3 * MB64);
    u16* X = Qb;  // aliases Qb (dead after QK)

    const int nv = (int)(((ll)B * S * D) / (8 * 256));
    cvt_bf16<<<nv, 256, 0, stream>>>(Q, Qb);
    cvt_bf16<<<nv, 256, 0, stream>>>(Km, Kb);
    transpose_cvt<<<dim3(D / 64, S / 64, B), 256, 0, stream>>>(V, Vt, S, D, SD, SD);
    transpose_cvt<<<dim3(E / 64, D / 64, 1), 256, 0, stream>>>(W, Wt, D, E, 0, 0);

    // QK (scale+mask fused): M=N=2048, K=1024, 16 batches -> nwg = 1024
    gemm8<0><<<dim3(1024), 512, 0, stream>>>(
        Qb, Kb, P, D, D, D, S, SD, SD, SS, pad, nullptr, 8, 64, 1024);
    softmax_rows<false><<<dim3(B * S / 4), 256, 0, stream>>>(P, pad);
    // PV: M=2048, N=1024, K=2048 -> nwg = 512
    gemm8<1><<<dim3(512), 512, 0, stream>>>(
        P, Vt, X, S, S, S, D, SS, SD, SD, nullptr, nullptr, 4, 32, 512);
    // out: M=32768, N=1024, K=1024 -> nwg = 512
    gemm8<2><<<dim3(512), 512, 0, stream>>>(
        X, Wt, out, D, D, D, E, 0, 0, 0, nullptr, bias, 4, 512, 512);
  } else if (ws_size >= 2 * MB64 + szWt) {
    // Tier B: fp32-input 128² QK; 8-phase PV/out.
    u16* Vt = (u16*)ws;
    u16* Wt = (u16*)(ws + MB64);
    u16* X = (u16*)(ws + MB64 + szWt);

    transpose_cvt<<<dim3(D / 64, S / 64, B), 256, 0, stream>>>(V, Vt, S, D, SD, SD);
    transpose_cvt<<<dim3(E / 64, D / 64, 1), 256, 0, stream>>>(W, Wt, D, E, 0, 0);
    gemm_f32in<<<dim3(S / 128, S / 128, B), 256, 0, stream>>>(
        Q, Km, P, D, D, D, S, SD, SD, SS);
    softmax_rows<true><<<dim3(B * S / 4), 256, 0, stream>>>(P, pad);
    gemm8<1><<<dim3(512), 512, 0, stream>>>(
        P, Vt, X, S, S, S, D, SS, SD, SD, nullptr, nullptr, 4, 32, 512);
    gemm8<2><<<dim3(512), 512, 0, stream>>>(
        X, Wt, out, D, D, D, E, 0, 0, 0, nullptr, bias, 4, 512, 512);
  } else {
    // Tier C: per-batch V transpose (needs >= 70 MB).
    u16* Wt = (u16*)ws;
    u16* Vtb = (u16*)(ws + szWt);
    u16* X = (u16*)(ws + szWt + (size_t)D * S * 2);

    transpose_cvt<<<dim3(E / 64, D / 64, 1), 256, 0, stream>>>(W, Wt, D, E, 0, 0);
    gemm_f32in<<<dim3(S / 128, S / 128, B), 256, 0, stream>>>(
        Q, Km, P, D, D, D, S, SD, SD, SS);
    softmax_rows<true><<<dim3(B * S / 4), 256, 0, stream>>>(P, pad);
    for (int b = 0; b < B; ++b) {
      transpose_cvt<<<dim3(D / 64, S / 64, 1), 256, 0, stream>>>(
          V + (ll)b * SD, Vtb, S, D, 0, 0);
      gemm8<1><<<dim3(32), 512, 0, stream>>>(
          P + (ll)b * SS, Vtb, X + (ll)b * SD, S, S, S, D, 0, 0, 0, nullptr,
          nullptr, 4, 32, 32);
    }
    gemm8<2><<<dim3(512), 512, 0, stream>>>(
        X, Wt, out, D, D, D, E, 0, 0, 0, nullptr, bias, 4, 512, 512);
  }
}